// Round 15
// baseline (139.893 us; speedup 1.0000x reference)
//
#include <hip/hip_runtime.h>
#include <math.h>

#define N_NODES 50000
#define N_EDGES 500000
#define IN_DIM 256
#define OUT_DIM 128
#define NEG_SLOPE 0.01f
#define NB_SCAN 196  // ceil(50000/256)

typedef __attribute__((ext_vector_type(8))) short short8;
typedef __attribute__((ext_vector_type(4))) float f32x4;

// fp32 -> bf16 bits, round-to-nearest-even
__device__ __forceinline__ unsigned short f2bf(float f) {
  unsigned u = __float_as_uint(f);
  unsigned r = (u + 0x7FFFu + ((u >> 16) & 1u)) >> 16;
  return (unsigned short)r;
}

// ---------------- W fp32 -> bf16 (32768 elements, one-shot) ----------------
__global__ __launch_bounds__(256) void wconv_kernel(
    const float* __restrict__ W, unsigned short* __restrict__ Wb) {
  int i = blockIdx.x * 256 + threadIdx.x;
  Wb[i] = f2bf(W[i]);
}

// ---------------- MFMA GEMM: z = h @ W^T (z stored bf16), fused s1/s2 ----------------
// MLP restructure: ALL 16 A-loads issued up front (64 VGPRs, static indexing),
// then fully-unrolled cvt+MFMA. B loads stay global (L1/L2-hot across waves).
// C/D: lane l, reg q -> row=(l>>4)*4+q, col=l&15   [m89-verified]
__global__ __launch_bounds__(256) void gemm_mfma_kernel(
    const float* __restrict__ h, const unsigned short* __restrict__ Wb,
    const float* __restrict__ aw,
    unsigned short* __restrict__ zb, float* __restrict__ s1, float* __restrict__ s2) {
  const int wid  = threadIdx.x >> 6;
  const int lane = threadIdx.x & 63;
  const int row0 = blockIdx.x * 64 + wid * 16;
  const int r16  = lane & 15;
  const int kg   = lane >> 4;

  f32x4 acc[8];
#pragma unroll
  for (int ct = 0; ct < 8; ++ct) acc[ct] = (f32x4)(0.f);

  const int arow = row0 + r16;
  const size_t hbase = (size_t)((arow < N_NODES) ? arow : (N_NODES - 1)) * IN_DIM;

  // issue all 16 A-loads (16B each) before any use: 16 outstanding VMEM ops
  float4 a0[8], a1[8];
#pragma unroll
  for (int ks = 0; ks < 8; ++ks) {
    const int k0 = ks * 32 + kg * 8;
    a0[ks] = *(const float4*)&h[hbase + k0];
    a1[ks] = *(const float4*)&h[hbase + k0 + 4];
  }

#pragma unroll
  for (int ks = 0; ks < 8; ++ks) {
    const int k0 = ks * 32 + kg * 8;
    short8 af;
    af[0] = (short)f2bf(a0[ks].x); af[1] = (short)f2bf(a0[ks].y);
    af[2] = (short)f2bf(a0[ks].z); af[3] = (short)f2bf(a0[ks].w);
    af[4] = (short)f2bf(a1[ks].x); af[5] = (short)f2bf(a1[ks].y);
    af[6] = (short)f2bf(a1[ks].z); af[7] = (short)f2bf(a1[ks].w);
#pragma unroll
    for (int ct = 0; ct < 8; ++ct) {
      const short8 bf = *(const short8*)&Wb[(size_t)(ct * 16 + r16) * IN_DIM + k0];
      acc[ct] = __builtin_amdgcn_mfma_f32_16x16x32_bf16(af, bf, acc[ct], 0, 0, 0);
    }
  }

#pragma unroll
  for (int q = 0; q < 4; ++q) {
    const int zr = row0 + kg * 4 + q;
    if (zr < N_NODES) {
#pragma unroll
      for (int ct = 0; ct < 8; ++ct)
        zb[(size_t)zr * OUT_DIM + ct * 16 + r16] = f2bf(acc[ct][q]);
    }
  }

  float p1[4] = {0.f, 0.f, 0.f, 0.f}, p2[4] = {0.f, 0.f, 0.f, 0.f};
#pragma unroll
  for (int ct = 0; ct < 8; ++ct) {
    const float w1 = aw[ct * 16 + r16];
    const float w2 = aw[128 + ct * 16 + r16];
#pragma unroll
    for (int q = 0; q < 4; ++q) {
      p1[q] += acc[ct][q] * w1;
      p2[q] += acc[ct][q] * w2;
    }
  }
#pragma unroll
  for (int off = 8; off; off >>= 1) {
#pragma unroll
    for (int q = 0; q < 4; ++q) {
      p1[q] += __shfl_xor(p1[q], off);
      p2[q] += __shfl_xor(p2[q], off);
    }
  }
  if (r16 == 0) {
#pragma unroll
    for (int q = 0; q < 4; ++q) {
      const int zr = row0 + kg * 4 + q;
      if (zr < N_NODES) { s1[zr] = p1[q]; s2[zr] = p2[q]; }
    }
  }
}

// ---------------- fused: dist mean + dst histogram + RANK capture ----------------
__global__ __launch_bounds__(256) void mean_hist_kernel(
    const int* __restrict__ dist, const int* __restrict__ dst,
    int* __restrict__ isum, int* __restrict__ cidx, int* __restrict__ rank) {
  int tid = blockIdx.x * blockDim.x + threadIdx.x;
  int stride = gridDim.x * blockDim.x;
  int acc = 0;
  for (int i = tid; i < N_EDGES; i += stride) {
    acc += dist[i];
    rank[i] = atomicAdd(&cidx[dst[i]], 1);
  }
#pragma unroll
  for (int off = 32; off; off >>= 1) acc += __shfl_down(acc, off);
  if ((threadIdx.x & 63) == 0) atomicAdd(isum, acc);
}

// ---------------- hierarchical scan: A) per-block excl scan + totals ----------------
__global__ __launch_bounds__(256) void scanA_kernel(
    int* __restrict__ c, int* __restrict__ bsum) {
  __shared__ int tmp[256];
  const int t = threadIdx.x;
  const int i = blockIdx.x * 256 + t;
  const int v = (i < N_NODES) ? c[i] : 0;
  tmp[t] = v;
  __syncthreads();
#pragma unroll
  for (int off = 1; off < 256; off <<= 1) {
    int u = (t >= off) ? tmp[t - off] : 0;
    __syncthreads();
    tmp[t] += u;
    __syncthreads();
  }
  if (i < N_NODES) c[i] = tmp[t] - v;          // exclusive within block
  if (t == 255) bsum[blockIdx.x] = tmp[255];   // block total
}

// ---------------- B) scan 196 block totals + pmf LUT (fused tail) ----------------
__global__ __launch_bounds__(256) void scanB_kernel(
    int* __restrict__ bsum, const int* __restrict__ isum, float* __restrict__ lut) {
  __shared__ int tmp[256];
  const int t = threadIdx.x;
  const int v = (t < NB_SCAN) ? bsum[t] : 0;
  tmp[t] = v;
  __syncthreads();
#pragma unroll
  for (int off = 1; off < 256; off <<= 1) {
    int u = (t >= off) ? tmp[t - off] : 0;
    __syncthreads();
    tmp[t] += u;
    __syncthreads();
  }
  if (t < NB_SCAN) bsum[t] = tmp[t] - v;       // exclusive block offsets
  if (t < 100) {                               // lut[d] = pmf(d>>1, mu)
    const float mu = (float)(*isum) * (1.0f / N_EDGES);
    const float k = (float)(t >> 1);
    lut[t] = expf(k * logf(mu) - mu - lgammaf(k + 1.0f));
  }
}

// ---------------- C) add block offsets (cidx becomes exclusive STARTS) ----------------
__global__ __launch_bounds__(256) void scanC_kernel(
    int* __restrict__ c, const int* __restrict__ bsum) {
  const int i = blockIdx.x * 256 + threadIdx.x;
  if (i < N_NODES) c[i] += bsum[blockIdx.x];
}

// ---------------- fill: ATOMIC-FREE CSR fill; one 8B (e,src) pair per edge ----------------
__global__ __launch_bounds__(256) void fill_kernel(
    const int* __restrict__ dst, const int* __restrict__ src,
    const int* __restrict__ dist, const int* __restrict__ rank,
    const float* __restrict__ s1, const float* __restrict__ s2,
    const float* __restrict__ lut, const int* __restrict__ starts,
    float2* __restrict__ epair) {
  int i = blockIdx.x * blockDim.x + threadIdx.x;
  if (i >= N_EDGES) return;
  const int d = dst[i];
  const int s = src[i];
  const float p = lut[dist[i]];
  const float a = s1[s] + s2[d];
  const float ev = p * ((a >= 0.f) ? a : NEG_SLOPE * a);
  const int pos = starts[d] + rank[i];
  epair[pos] = make_float2(ev, __int_as_float(s));
}

// ---------------- node kernel: one wave per dst node ----------------
__global__ __launch_bounds__(256) void node_kernel(
    const int* __restrict__ cidx, const float2* __restrict__ epair,
    const unsigned* __restrict__ zbu, float* __restrict__ out) {
  const int wid = threadIdx.x >> 6, lane = threadIdx.x & 63;
  const int n = blockIdx.x * 4 + wid;
  if (n >= N_NODES) return;
  const int beg = cidx[n];
  const int end = (n + 1 < N_NODES) ? cidx[n + 1] : N_EDGES;
  const int deg = end - beg;

  float2 acc = make_float2(0.f, 0.f);
  if (deg > 0) {
    float m, ssum;
    if (deg <= 64) {
      float e0 = (lane < deg) ? epair[beg + lane].x : -INFINITY;
      m = e0;
#pragma unroll
      for (int off = 32; off; off >>= 1) m = fmaxf(m, __shfl_xor(m, off));
      ssum = expf(e0 - m);   // 0 for invalid lanes
#pragma unroll
      for (int off = 32; off; off >>= 1) ssum += __shfl_xor(ssum, off);
    } else {
      float mm = -INFINITY;
      for (int j = lane; j < deg; j += 64) mm = fmaxf(mm, epair[beg + j].x);
      m = mm;
#pragma unroll
      for (int off = 32; off; off >>= 1) m = fmaxf(m, __shfl_xor(m, off));
      float ss = 0.f;
      for (int j = lane; j < deg; j += 64) ss += expf(epair[beg + j].x - m);
      ssum = ss;
#pragma unroll
      for (int off = 32; off; off >>= 1) ssum += __shfl_xor(ssum, off);
    }
    const float inv = 1.0f / ssum;

    // walk: wave-uniform 8B pair load per edge; unrolled overlapped row gathers
#pragma unroll 4
    for (int jj = 0; jj < deg; ++jj) {
      const float2 pr = epair[beg + jj];
      const float al = expf(pr.x - m) * inv;
      const int   sj = __float_as_int(pr.y);
      const unsigned v = zbu[(size_t)sj * 64 + lane];
      acc.x += al * __uint_as_float((v & 0xFFFFu) << 16);
      acc.y += al * __uint_as_float(v & 0xFFFF0000u);
    }
  }
  *(float2*)&out[(size_t)n * OUT_DIM + lane * 2] = acc;
}

extern "C" void kernel_launch(void* const* d_in, const int* in_sizes, int n_in,
                              void* d_out, int out_size, void* d_ws, size_t ws_size,
                              hipStream_t stream) {
  const float* h    = (const float*)d_in[0];
  const float* fc_w = (const float*)d_in[1];
  const float* attn = (const float*)d_in[2];
  const int*   src  = (const int*)d_in[3];
  const int*   dst  = (const int*)d_in[4];
  const int*   dist = (const int*)d_in[5];
  float* out = (float*)d_out;
  float* ws  = (float*)d_ws;

  // workspace layout (4-byte units), total 4,866,684 words = 19.5 MB
  unsigned short* zb    = (unsigned short*)ws;        // 6,400,000 bf16 = 3,200,000 words
  float*          s1    = ws + 3200000;               //    50,000
  float*          s2    = ws + 3250000;               //    50,000
  int*            cidx  = (int*)(ws + 3300000);       //    50,000 (counts -> starts)
  int*            isum  = (int*)(ws + 3350000);       //         1
  float*          lut   = ws + 3350004;               //       100
  int*            rank  = (int*)(ws + 3350104);       //   500,000
  float2*         epair = (float2*)(ws + 3850104);    //   500,000 pairs (1M words, 8B-aligned)
  unsigned short* Wb    = (unsigned short*)(ws + 4850104); // 32,768 bf16
  int*            bsum  = (int*)(ws + 4866488);       //       196

  hipMemsetAsync(cidx, 0, (size_t)50001 * sizeof(int), stream);  // cidx + isum

  wconv_kernel<<<(IN_DIM * OUT_DIM) / 256, 256, 0, stream>>>(fc_w, Wb);
  gemm_mfma_kernel<<<(N_NODES + 63) / 64, 256, 0, stream>>>(h, Wb, attn, zb, s1, s2);
  mean_hist_kernel<<<256, 256, 0, stream>>>(dist, dst, isum, cidx, rank);
  scanA_kernel<<<NB_SCAN, 256, 0, stream>>>(cidx, bsum);
  scanB_kernel<<<1, 256, 0, stream>>>(bsum, isum, lut);
  scanC_kernel<<<NB_SCAN, 256, 0, stream>>>(cidx, bsum);
  fill_kernel<<<(N_EDGES + 255) / 256, 256, 0, stream>>>(
      dst, src, dist, rank, s1, s2, lut, cidx, epair);
  node_kernel<<<(N_NODES + 3) / 4, 256, 0, stream>>>(
      cidx, epair, (const unsigned*)zb, out);
}

// Round 16
// 115.325 us; speedup vs baseline: 1.2130x; 1.2130x over previous
//
#include <hip/hip_runtime.h>
#include <math.h>

#define N_NODES 50000
#define N_EDGES 500000
#define IN_DIM 256
#define OUT_DIM 128
#define NEG_SLOPE 0.01f
#define NB_SCAN 196  // ceil(50000/256)

typedef __attribute__((ext_vector_type(8))) short short8;
typedef __attribute__((ext_vector_type(4))) float f32x4;

// fp32 -> bf16 bits, round-to-nearest-even
__device__ __forceinline__ unsigned short f2bf(float f) {
  unsigned u = __float_as_uint(f);
  unsigned r = (u + 0x7FFFu + ((u >> 16) & 1u)) >> 16;
  return (unsigned short)r;
}

// ---------------- W fp32 -> bf16 (32768 elements, one-shot) ----------------
__global__ __launch_bounds__(256) void wconv_kernel(
    const float* __restrict__ W, unsigned short* __restrict__ Wb) {
  int i = blockIdx.x * 256 + threadIdx.x;
  Wb[i] = f2bf(W[i]);
}

// ---------------- MFMA GEMM: z = h @ W^T (z bf16), fused s1/s2 ----------------
// LDS-staged B: full Wb (128x256 bf16 = 64KB) staged once per block with XOR
// swizzle (elem k ^= (row&7)<<3) -> ds_read_b128 at row-stride 512B is 2-way
// (free) instead of 16-way. 512-thread blocks, launch_bounds(512,4):
// 2 blocks/CU (LDS-limited) = 4 waves/SIMD; VGPR cap 128 lets the 16 hoisted
// A-loads stay live (round-15 failure: 60-VGPR budget undid the hoist).
// C/D: lane l, reg q -> row=(l>>4)*4+q, col=l&15   [m89-verified]
__global__ __launch_bounds__(512, 4) void gemm_mfma_kernel(
    const float* __restrict__ h, const unsigned short* __restrict__ Wb,
    const float* __restrict__ aw,
    unsigned short* __restrict__ zb, float* __restrict__ s1, float* __restrict__ s2) {
  __shared__ unsigned short Blds[128 * 256];  // 64 KB
  const int t    = threadIdx.x;
  const int wid  = t >> 6;
  const int lane = t & 63;
  const int row0 = blockIdx.x * 128 + wid * 16;
  const int r16  = lane & 15;
  const int kg   = lane >> 4;

  // stage Wb -> LDS, swizzled: elem (row, k8*8) -> Blds[row*256 + ((k8^(row&7))*8)]
#pragma unroll
  for (int it = 0; it < 8; ++it) {
    const int c   = it * 512 + t;        // 16B-chunk id, 4096 total
    const int row = c >> 5, kc = c & 31;
    *(float4*)&Blds[row * 256 + ((kc ^ (row & 7)) << 3)] =
        *(const float4*)&Wb[row * 256 + (kc << 3)];
  }

  // hoist all 16 A-loads while staging is in flight
  const int arow = row0 + r16;
  const size_t hbase = (size_t)((arow < N_NODES) ? arow : (N_NODES - 1)) * IN_DIM;
  float4 a0[8], a1[8];
#pragma unroll
  for (int ks = 0; ks < 8; ++ks) {
    const int k0 = ks * 32 + kg * 8;
    a0[ks] = *(const float4*)&h[hbase + k0];
    a1[ks] = *(const float4*)&h[hbase + k0 + 4];
  }

  f32x4 acc[8];
#pragma unroll
  for (int ct = 0; ct < 8; ++ct) acc[ct] = (f32x4)(0.f);

  __syncthreads();

#pragma unroll
  for (int ks = 0; ks < 8; ++ks) {
    const int k0 = ks * 32 + kg * 8;
    short8 af;
    af[0] = (short)f2bf(a0[ks].x); af[1] = (short)f2bf(a0[ks].y);
    af[2] = (short)f2bf(a0[ks].z); af[3] = (short)f2bf(a0[ks].w);
    af[4] = (short)f2bf(a1[ks].x); af[5] = (short)f2bf(a1[ks].y);
    af[6] = (short)f2bf(a1[ks].z); af[7] = (short)f2bf(a1[ks].w);
#pragma unroll
    for (int ct = 0; ct < 8; ++ct) {
      const int brow = ct * 16 + r16;
      const short8 bf =
          *(const short8*)&Blds[brow * 256 + (k0 ^ ((r16 & 7) << 3))];
      acc[ct] = __builtin_amdgcn_mfma_f32_16x16x32_bf16(af, bf, acc[ct], 0, 0, 0);
    }
  }

#pragma unroll
  for (int q = 0; q < 4; ++q) {
    const int zr = row0 + kg * 4 + q;
    if (zr < N_NODES) {
#pragma unroll
      for (int ct = 0; ct < 8; ++ct)
        zb[(size_t)zr * OUT_DIM + ct * 16 + r16] = f2bf(acc[ct][q]);
    }
  }

  float p1[4] = {0.f, 0.f, 0.f, 0.f}, p2[4] = {0.f, 0.f, 0.f, 0.f};
#pragma unroll
  for (int ct = 0; ct < 8; ++ct) {
    const float w1 = aw[ct * 16 + r16];
    const float w2 = aw[128 + ct * 16 + r16];
#pragma unroll
    for (int q = 0; q < 4; ++q) {
      p1[q] += acc[ct][q] * w1;
      p2[q] += acc[ct][q] * w2;
    }
  }
#pragma unroll
  for (int off = 8; off; off >>= 1) {
#pragma unroll
    for (int q = 0; q < 4; ++q) {
      p1[q] += __shfl_xor(p1[q], off);
      p2[q] += __shfl_xor(p2[q], off);
    }
  }
  if (r16 == 0) {
#pragma unroll
    for (int q = 0; q < 4; ++q) {
      const int zr = row0 + kg * 4 + q;
      if (zr < N_NODES) { s1[zr] = p1[q]; s2[zr] = p2[q]; }
    }
  }
}

// ---------------- fused: dist mean + dst histogram + RANK capture ----------------
__global__ __launch_bounds__(256) void mean_hist_kernel(
    const int* __restrict__ dist, const int* __restrict__ dst,
    int* __restrict__ isum, int* __restrict__ cidx, int* __restrict__ rank) {
  int tid = blockIdx.x * blockDim.x + threadIdx.x;
  int stride = gridDim.x * blockDim.x;
  int acc = 0;
  for (int i = tid; i < N_EDGES; i += stride) {
    acc += dist[i];
    rank[i] = atomicAdd(&cidx[dst[i]], 1);
  }
#pragma unroll
  for (int off = 32; off; off >>= 1) acc += __shfl_down(acc, off);
  if ((threadIdx.x & 63) == 0) atomicAdd(isum, acc);
}

// ---------------- hierarchical scan: A) per-block excl scan + totals ----------------
__global__ __launch_bounds__(256) void scanA_kernel(
    int* __restrict__ c, int* __restrict__ bsum) {
  __shared__ int tmp[256];
  const int t = threadIdx.x;
  const int i = blockIdx.x * 256 + t;
  const int v = (i < N_NODES) ? c[i] : 0;
  tmp[t] = v;
  __syncthreads();
#pragma unroll
  for (int off = 1; off < 256; off <<= 1) {
    int u = (t >= off) ? tmp[t - off] : 0;
    __syncthreads();
    tmp[t] += u;
    __syncthreads();
  }
  if (i < N_NODES) c[i] = tmp[t] - v;          // exclusive within block
  if (t == 255) bsum[blockIdx.x] = tmp[255];   // block total
}

// ---------------- B) scan 196 block totals + pmf LUT (fused tail) ----------------
__global__ __launch_bounds__(256) void scanB_kernel(
    int* __restrict__ bsum, const int* __restrict__ isum, float* __restrict__ lut) {
  __shared__ int tmp[256];
  const int t = threadIdx.x;
  const int v = (t < NB_SCAN) ? bsum[t] : 0;
  tmp[t] = v;
  __syncthreads();
#pragma unroll
  for (int off = 1; off < 256; off <<= 1) {
    int u = (t >= off) ? tmp[t - off] : 0;
    __syncthreads();
    tmp[t] += u;
    __syncthreads();
  }
  if (t < NB_SCAN) bsum[t] = tmp[t] - v;       // exclusive block offsets
  if (t < 100) {                               // lut[d] = pmf(d>>1, mu)
    const float mu = (float)(*isum) * (1.0f / N_EDGES);
    const float k = (float)(t >> 1);
    lut[t] = expf(k * logf(mu) - mu - lgammaf(k + 1.0f));
  }
}

// ---------------- C) add block offsets (cidx becomes exclusive STARTS) ----------------
__global__ __launch_bounds__(256) void scanC_kernel(
    int* __restrict__ c, const int* __restrict__ bsum) {
  const int i = blockIdx.x * 256 + threadIdx.x;
  if (i < N_NODES) c[i] += bsum[blockIdx.x];
}

// ---------------- fill: ATOMIC-FREE CSR fill; one 8B (e,src) pair per edge ----------------
__global__ __launch_bounds__(256) void fill_kernel(
    const int* __restrict__ dst, const int* __restrict__ src,
    const int* __restrict__ dist, const int* __restrict__ rank,
    const float* __restrict__ s1, const float* __restrict__ s2,
    const float* __restrict__ lut, const int* __restrict__ starts,
    float2* __restrict__ epair) {
  int i = blockIdx.x * blockDim.x + threadIdx.x;
  if (i >= N_EDGES) return;
  const int d = dst[i];
  const int s = src[i];
  const float p = lut[dist[i]];
  const float a = s1[s] + s2[d];
  const float ev = p * ((a >= 0.f) ? a : NEG_SLOPE * a);
  const int pos = starts[d] + rank[i];
  epair[pos] = make_float2(ev, __int_as_float(s));
}

// ---------------- node kernel: one wave per dst node ----------------
__global__ __launch_bounds__(256) void node_kernel(
    const int* __restrict__ cidx, const float2* __restrict__ epair,
    const unsigned* __restrict__ zbu, float* __restrict__ out) {
  const int wid = threadIdx.x >> 6, lane = threadIdx.x & 63;
  const int n = blockIdx.x * 4 + wid;
  if (n >= N_NODES) return;
  const int beg = cidx[n];
  const int end = (n + 1 < N_NODES) ? cidx[n + 1] : N_EDGES;
  const int deg = end - beg;

  float2 acc = make_float2(0.f, 0.f);
  if (deg > 0) {
    float m, ssum;
    if (deg <= 64) {
      float e0 = (lane < deg) ? epair[beg + lane].x : -INFINITY;
      m = e0;
#pragma unroll
      for (int off = 32; off; off >>= 1) m = fmaxf(m, __shfl_xor(m, off));
      ssum = expf(e0 - m);   // 0 for invalid lanes
#pragma unroll
      for (int off = 32; off; off >>= 1) ssum += __shfl_xor(ssum, off);
    } else {
      float mm = -INFINITY;
      for (int j = lane; j < deg; j += 64) mm = fmaxf(mm, epair[beg + j].x);
      m = mm;
#pragma unroll
      for (int off = 32; off; off >>= 1) m = fmaxf(m, __shfl_xor(m, off));
      float ss = 0.f;
      for (int j = lane; j < deg; j += 64) ss += expf(epair[beg + j].x - m);
      ssum = ss;
#pragma unroll
      for (int off = 32; off; off >>= 1) ssum += __shfl_xor(ssum, off);
    }
    const float inv = 1.0f / ssum;

    // walk: wave-uniform 8B pair load per edge; unrolled overlapped row gathers
#pragma unroll 4
    for (int jj = 0; jj < deg; ++jj) {
      const float2 pr = epair[beg + jj];
      const float al = expf(pr.x - m) * inv;
      const int   sj = __float_as_int(pr.y);
      const unsigned v = zbu[(size_t)sj * 64 + lane];
      acc.x += al * __uint_as_float((v & 0xFFFFu) << 16);
      acc.y += al * __uint_as_float(v & 0xFFFF0000u);
    }
  }
  *(float2*)&out[(size_t)n * OUT_DIM + lane * 2] = acc;
}

extern "C" void kernel_launch(void* const* d_in, const int* in_sizes, int n_in,
                              void* d_out, int out_size, void* d_ws, size_t ws_size,
                              hipStream_t stream) {
  const float* h    = (const float*)d_in[0];
  const float* fc_w = (const float*)d_in[1];
  const float* attn = (const float*)d_in[2];
  const int*   src  = (const int*)d_in[3];
  const int*   dst  = (const int*)d_in[4];
  const int*   dist = (const int*)d_in[5];
  float* out = (float*)d_out;
  float* ws  = (float*)d_ws;

  // workspace layout (4-byte units), total 4,866,684 words = 19.5 MB
  unsigned short* zb    = (unsigned short*)ws;        // 6,400,000 bf16 = 3,200,000 words
  float*          s1    = ws + 3200000;               //    50,000
  float*          s2    = ws + 3250000;               //    50,000
  int*            cidx  = (int*)(ws + 3300000);       //    50,000 (counts -> starts)
  int*            isum  = (int*)(ws + 3350000);       //         1
  float*          lut   = ws + 3350004;               //       100
  int*            rank  = (int*)(ws + 3350104);       //   500,000
  float2*         epair = (float2*)(ws + 3850104);    //   500,000 pairs (1M words, 8B-aligned)
  unsigned short* Wb    = (unsigned short*)(ws + 4850104); // 32,768 bf16
  int*            bsum  = (int*)(ws + 4866488);       //       196

  hipMemsetAsync(cidx, 0, (size_t)50001 * sizeof(int), stream);  // cidx + isum

  wconv_kernel<<<(IN_DIM * OUT_DIM) / 256, 256, 0, stream>>>(fc_w, Wb);
  gemm_mfma_kernel<<<(N_NODES + 127) / 128, 512, 0, stream>>>(h, Wb, attn, zb, s1, s2);
  mean_hist_kernel<<<256, 256, 0, stream>>>(dist, dst, isum, cidx, rank);
  scanA_kernel<<<NB_SCAN, 256, 0, stream>>>(cidx, bsum);
  scanB_kernel<<<1, 256, 0, stream>>>(bsum, isum, lut);
  scanC_kernel<<<NB_SCAN, 256, 0, stream>>>(cidx, bsum);
  fill_kernel<<<(N_EDGES + 255) / 256, 256, 0, stream>>>(
      dst, src, dist, rank, s1, s2, lut, cidx, epair);
  node_kernel<<<(N_NODES + 3) / 4, 256, 0, stream>>>(
      cidx, epair, (const unsigned*)zb, out);
}

// Round 17
// 112.926 us; speedup vs baseline: 1.2388x; 1.0212x over previous
//
#include <hip/hip_runtime.h>
#include <math.h>

#define N_NODES 50000
#define N_EDGES 500000
#define IN_DIM 256
#define OUT_DIM 128
#define NEG_SLOPE 0.01f
#define NB_SCAN 196  // ceil(50000/256)

typedef __attribute__((ext_vector_type(8))) short short8;
typedef __attribute__((ext_vector_type(4))) float f32x4;

// fp32 -> bf16 bits, round-to-nearest-even
__device__ __forceinline__ unsigned short f2bf(float f) {
  unsigned u = __float_as_uint(f);
  unsigned r = (u + 0x7FFFu + ((u >> 16) & 1u)) >> 16;
  return (unsigned short)r;
}

// ---------------- zero cidx+isum (50001 ints) — replaces 39us runtime memset ----------------
__global__ __launch_bounds__(256) void zero_kernel(int* __restrict__ p) {
  const int i = blockIdx.x * 256 + threadIdx.x;
  if (i < N_NODES + 1) p[i] = 0;
}

// ---------------- W fp32 -> bf16 (32768 elements, one-shot) ----------------
__global__ __launch_bounds__(256) void wconv_kernel(
    const float* __restrict__ W, unsigned short* __restrict__ Wb) {
  int i = blockIdx.x * 256 + threadIdx.x;
  Wb[i] = f2bf(W[i]);
}

// ---------------- MFMA GEMM: z = h @ W^T (z bf16), fused s1/s2 ----------------
// LDS-staged B (64KB, XOR-swizzled); 512 threads, launch_bounds(512,4);
// 16 A-loads hoisted (fits the 128-VGPR budget).
// C/D: lane l, reg q -> row=(l>>4)*4+q, col=l&15   [m89-verified]
__global__ __launch_bounds__(512, 4) void gemm_mfma_kernel(
    const float* __restrict__ h, const unsigned short* __restrict__ Wb,
    const float* __restrict__ aw,
    unsigned short* __restrict__ zb, float* __restrict__ s1, float* __restrict__ s2) {
  __shared__ unsigned short Blds[128 * 256];  // 64 KB
  const int t    = threadIdx.x;
  const int wid  = t >> 6;
  const int lane = t & 63;
  const int row0 = blockIdx.x * 128 + wid * 16;
  const int r16  = lane & 15;
  const int kg   = lane >> 4;

  // stage Wb -> LDS, swizzled: elem (row, k8*8) -> Blds[row*256 + ((k8^(row&7))*8)]
#pragma unroll
  for (int it = 0; it < 8; ++it) {
    const int c   = it * 512 + t;        // 16B-chunk id, 4096 total
    const int row = c >> 5, kc = c & 31;
    *(float4*)&Blds[row * 256 + ((kc ^ (row & 7)) << 3)] =
        *(const float4*)&Wb[row * 256 + (kc << 3)];
  }

  // hoist all 16 A-loads while staging is in flight
  const int arow = row0 + r16;
  const size_t hbase = (size_t)((arow < N_NODES) ? arow : (N_NODES - 1)) * IN_DIM;
  float4 a0[8], a1[8];
#pragma unroll
  for (int ks = 0; ks < 8; ++ks) {
    const int k0 = ks * 32 + kg * 8;
    a0[ks] = *(const float4*)&h[hbase + k0];
    a1[ks] = *(const float4*)&h[hbase + k0 + 4];
  }

  f32x4 acc[8];
#pragma unroll
  for (int ct = 0; ct < 8; ++ct) acc[ct] = (f32x4)(0.f);

  __syncthreads();

#pragma unroll
  for (int ks = 0; ks < 8; ++ks) {
    const int k0 = ks * 32 + kg * 8;
    short8 af;
    af[0] = (short)f2bf(a0[ks].x); af[1] = (short)f2bf(a0[ks].y);
    af[2] = (short)f2bf(a0[ks].z); af[3] = (short)f2bf(a0[ks].w);
    af[4] = (short)f2bf(a1[ks].x); af[5] = (short)f2bf(a1[ks].y);
    af[6] = (short)f2bf(a1[ks].z); af[7] = (short)f2bf(a1[ks].w);
#pragma unroll
    for (int ct = 0; ct < 8; ++ct) {
      const int brow = ct * 16 + r16;
      const short8 bf =
          *(const short8*)&Blds[brow * 256 + (k0 ^ ((r16 & 7) << 3))];
      acc[ct] = __builtin_amdgcn_mfma_f32_16x16x32_bf16(af, bf, acc[ct], 0, 0, 0);
    }
  }

#pragma unroll
  for (int q = 0; q < 4; ++q) {
    const int zr = row0 + kg * 4 + q;
    if (zr < N_NODES) {
#pragma unroll
      for (int ct = 0; ct < 8; ++ct)
        zb[(size_t)zr * OUT_DIM + ct * 16 + r16] = f2bf(acc[ct][q]);
    }
  }

  float p1[4] = {0.f, 0.f, 0.f, 0.f}, p2[4] = {0.f, 0.f, 0.f, 0.f};
#pragma unroll
  for (int ct = 0; ct < 8; ++ct) {
    const float w1 = aw[ct * 16 + r16];
    const float w2 = aw[128 + ct * 16 + r16];
#pragma unroll
    for (int q = 0; q < 4; ++q) {
      p1[q] += acc[ct][q] * w1;
      p2[q] += acc[ct][q] * w2;
    }
  }
#pragma unroll
  for (int off = 8; off; off >>= 1) {
#pragma unroll
    for (int q = 0; q < 4; ++q) {
      p1[q] += __shfl_xor(p1[q], off);
      p2[q] += __shfl_xor(p2[q], off);
    }
  }
  if (r16 == 0) {
#pragma unroll
    for (int q = 0; q < 4; ++q) {
      const int zr = row0 + kg * 4 + q;
      if (zr < N_NODES) { s1[zr] = p1[q]; s2[zr] = p2[q]; }
    }
  }
}

// ---------------- fused: dist mean + dst histogram + RANK capture ----------------
__global__ __launch_bounds__(256) void mean_hist_kernel(
    const int* __restrict__ dist, const int* __restrict__ dst,
    int* __restrict__ isum, int* __restrict__ cidx, int* __restrict__ rank) {
  int tid = blockIdx.x * blockDim.x + threadIdx.x;
  int stride = gridDim.x * blockDim.x;
  int acc = 0;
  for (int i = tid; i < N_EDGES; i += stride) {
    acc += dist[i];
    rank[i] = atomicAdd(&cidx[dst[i]], 1);
  }
#pragma unroll
  for (int off = 32; off; off >>= 1) acc += __shfl_down(acc, off);
  if ((threadIdx.x & 63) == 0) atomicAdd(isum, acc);
}

// ---------------- hierarchical scan: A) per-block excl scan + totals ----------------
__global__ __launch_bounds__(256) void scanA_kernel(
    int* __restrict__ c, int* __restrict__ bsum) {
  __shared__ int tmp[256];
  const int t = threadIdx.x;
  const int i = blockIdx.x * 256 + t;
  const int v = (i < N_NODES) ? c[i] : 0;
  tmp[t] = v;
  __syncthreads();
#pragma unroll
  for (int off = 1; off < 256; off <<= 1) {
    int u = (t >= off) ? tmp[t - off] : 0;
    __syncthreads();
    tmp[t] += u;
    __syncthreads();
  }
  if (i < N_NODES) c[i] = tmp[t] - v;          // exclusive within block
  if (t == 255) bsum[blockIdx.x] = tmp[255];   // block total
}

// ---------------- B) scan 196 block totals + pmf LUT (fused tail) ----------------
__global__ __launch_bounds__(256) void scanB_kernel(
    int* __restrict__ bsum, const int* __restrict__ isum, float* __restrict__ lut) {
  __shared__ int tmp[256];
  const int t = threadIdx.x;
  const int v = (t < NB_SCAN) ? bsum[t] : 0;
  tmp[t] = v;
  __syncthreads();
#pragma unroll
  for (int off = 1; off < 256; off <<= 1) {
    int u = (t >= off) ? tmp[t - off] : 0;
    __syncthreads();
    tmp[t] += u;
    __syncthreads();
  }
  if (t < NB_SCAN) bsum[t] = tmp[t] - v;       // exclusive block offsets
  if (t < 100) {                               // lut[d] = pmf(d>>1, mu)
    const float mu = (float)(*isum) * (1.0f / N_EDGES);
    const float k = (float)(t >> 1);
    lut[t] = expf(k * logf(mu) - mu - lgammaf(k + 1.0f));
  }
}

// ---------------- C) add block offsets (cidx becomes exclusive STARTS) ----------------
__global__ __launch_bounds__(256) void scanC_kernel(
    int* __restrict__ c, const int* __restrict__ bsum) {
  const int i = blockIdx.x * 256 + threadIdx.x;
  if (i < N_NODES) c[i] += bsum[blockIdx.x];
}

// ---------------- fill: ATOMIC-FREE CSR fill; one 8B (e,src) pair per edge ----------------
__global__ __launch_bounds__(256) void fill_kernel(
    const int* __restrict__ dst, const int* __restrict__ src,
    const int* __restrict__ dist, const int* __restrict__ rank,
    const float* __restrict__ s1, const float* __restrict__ s2,
    const float* __restrict__ lut, const int* __restrict__ starts,
    float2* __restrict__ epair) {
  int i = blockIdx.x * blockDim.x + threadIdx.x;
  if (i >= N_EDGES) return;
  const int d = dst[i];
  const int s = src[i];
  const float p = lut[dist[i]];
  const float a = s1[s] + s2[d];
  const float ev = p * ((a >= 0.f) ? a : NEG_SLOPE * a);
  const int pos = starts[d] + rank[i];
  epair[pos] = make_float2(ev, __int_as_float(s));
}

// ---------------- node kernel: one wave per dst node ----------------
__global__ __launch_bounds__(256) void node_kernel(
    const int* __restrict__ cidx, const float2* __restrict__ epair,
    const unsigned* __restrict__ zbu, float* __restrict__ out) {
  const int wid = threadIdx.x >> 6, lane = threadIdx.x & 63;
  const int n = blockIdx.x * 4 + wid;
  if (n >= N_NODES) return;
  const int beg = cidx[n];
  const int end = (n + 1 < N_NODES) ? cidx[n + 1] : N_EDGES;
  const int deg = end - beg;

  float2 acc = make_float2(0.f, 0.f);
  if (deg > 0) {
    float m, ssum;
    if (deg <= 64) {
      float e0 = (lane < deg) ? epair[beg + lane].x : -INFINITY;
      m = e0;
#pragma unroll
      for (int off = 32; off; off >>= 1) m = fmaxf(m, __shfl_xor(m, off));
      ssum = expf(e0 - m);   // 0 for invalid lanes
#pragma unroll
      for (int off = 32; off; off >>= 1) ssum += __shfl_xor(ssum, off);
    } else {
      float mm = -INFINITY;
      for (int j = lane; j < deg; j += 64) mm = fmaxf(mm, epair[beg + j].x);
      m = mm;
#pragma unroll
      for (int off = 32; off; off >>= 1) m = fmaxf(m, __shfl_xor(m, off));
      float ss = 0.f;
      for (int j = lane; j < deg; j += 64) ss += expf(epair[beg + j].x - m);
      ssum = ss;
#pragma unroll
      for (int off = 32; off; off >>= 1) ssum += __shfl_xor(ssum, off);
    }
    const float inv = 1.0f / ssum;

    // walk: wave-uniform 8B pair load per edge; unrolled overlapped row gathers
#pragma unroll 4
    for (int jj = 0; jj < deg; ++jj) {
      const float2 pr = epair[beg + jj];
      const float al = expf(pr.x - m) * inv;
      const int   sj = __float_as_int(pr.y);
      const unsigned v = zbu[(size_t)sj * 64 + lane];
      acc.x += al * __uint_as_float((v & 0xFFFFu) << 16);
      acc.y += al * __uint_as_float(v & 0xFFFF0000u);
    }
  }
  *(float2*)&out[(size_t)n * OUT_DIM + lane * 2] = acc;
}

extern "C" void kernel_launch(void* const* d_in, const int* in_sizes, int n_in,
                              void* d_out, int out_size, void* d_ws, size_t ws_size,
                              hipStream_t stream) {
  const float* h    = (const float*)d_in[0];
  const float* fc_w = (const float*)d_in[1];
  const float* attn = (const float*)d_in[2];
  const int*   src  = (const int*)d_in[3];
  const int*   dst  = (const int*)d_in[4];
  const int*   dist = (const int*)d_in[5];
  float* out = (float*)d_out;
  float* ws  = (float*)d_ws;

  // workspace layout (4-byte units), total 4,866,684 words = 19.5 MB
  unsigned short* zb    = (unsigned short*)ws;        // 6,400,000 bf16 = 3,200,000 words
  float*          s1    = ws + 3200000;               //    50,000
  float*          s2    = ws + 3250000;               //    50,000
  int*            cidx  = (int*)(ws + 3300000);       //    50,000 (counts -> starts)
  int*            isum  = (int*)(ws + 3350000);       //         1
  float*          lut   = ws + 3350004;               //       100
  int*            rank  = (int*)(ws + 3350104);       //   500,000
  float2*         epair = (float2*)(ws + 3850104);    //   500,000 pairs (1M words, 8B-aligned)
  unsigned short* Wb    = (unsigned short*)(ws + 4850104); // 32,768 bf16
  int*            bsum  = (int*)(ws + 4866488);       //       196

  zero_kernel<<<NB_SCAN, 256, 0, stream>>>(cidx);  // cidx + isum (contiguous)
  wconv_kernel<<<(IN_DIM * OUT_DIM) / 256, 256, 0, stream>>>(fc_w, Wb);
  gemm_mfma_kernel<<<(N_NODES + 127) / 128, 512, 0, stream>>>(h, Wb, attn, zb, s1, s2);
  mean_hist_kernel<<<256, 256, 0, stream>>>(dist, dst, isum, cidx, rank);
  scanA_kernel<<<NB_SCAN, 256, 0, stream>>>(cidx, bsum);
  scanB_kernel<<<1, 256, 0, stream>>>(bsum, isum, lut);
  scanC_kernel<<<NB_SCAN, 256, 0, stream>>>(cidx, bsum);
  fill_kernel<<<(N_EDGES + 255) / 256, 256, 0, stream>>>(
      dst, src, dist, rank, s1, s2, lut, cidx, epair);
  node_kernel<<<(N_NODES + 3) / 4, 256, 0, stream>>>(
      cidx, epair, (const unsigned*)zb, out);
}